// Round 9
// baseline (1652.744 us; speedup 1.0000x reference)
//
#include <hip/hip_runtime.h>

typedef unsigned short u16;
typedef unsigned int   u32;
typedef __attribute__((ext_vector_type(8))) short short8;
typedef __attribute__((ext_vector_type(4))) float f32x4;

#define DD      768
#define KK      6144   /* 8*768 : [root | W0..W6] concatenated on K */
#define NREL    7
#define NLAYERS 5

__device__ __forceinline__ float b2f(u16 v) {
  return __uint_as_float(((u32)v) << 16);
}
__device__ __forceinline__ u16 f2bf(float f) {
  u32 x = __float_as_uint(f);
  x += 0x7fffu + ((x >> 16) & 1u);
  return (u16)(x >> 16);
}
__device__ __forceinline__ void gload16(const void* g, void* l) {
  __builtin_amdgcn_global_load_lds(
      (const __attribute__((address_space(1))) void*)g,
      (__attribute__((address_space(3))) void*)l, 16, 0, 0);
}

// ---------- setup kernels ----------

__global__ void cast_x_kernel(const float* __restrict__ x, u16* __restrict__ H, size_t n) {
  for (size_t i = ((size_t)blockIdx.x * 256 + threadIdx.x) * 4; i < n; i += (size_t)gridDim.x * 256 * 4) {
    float4 v = *(const float4*)&x[i];
    u32 lo = (u32)f2bf(v.x) | ((u32)f2bf(v.y) << 16);
    u32 hi = (u32)f2bf(v.z) | ((u32)f2bf(v.w) << 16);
    uint2 o; o.x = lo; o.y = hi;
    *(uint2*)&H[i] = o;
  }
}

__global__ void count_kernel(const int* __restrict__ eidx, const int* __restrict__ etype,
                             int* cnt_dst, int* cnt_rel, int E, int Nn) {
  int e = blockIdx.x * 256 + threadIdx.x;
  if (e >= E) return;
  int dst = eidx[E + e];
  int rel = etype[e] + 1;
  atomicAdd(&cnt_dst[dst], 1);
  atomicAdd(&cnt_rel[(size_t)rel * Nn + dst], 1);
}

__global__ __launch_bounds__(1024) void scan_kernel(const int* __restrict__ cnt, int* __restrict__ offs, int n) {
  __shared__ int part[1024];
  int t = threadIdx.x;
  int per = (n + 1023) / 1024;
  int base = t * per;
  int s = 0;
  for (int i = 0; i < per; ++i) { int idx = base + i; if (idx < n) s += cnt[idx]; }
  part[t] = s;
  __syncthreads();
  for (int o = 1; o < 1024; o <<= 1) {
    int v = (t >= o) ? part[t - o] : 0;
    __syncthreads();
    part[t] += v;
    __syncthreads();
  }
  int excl = (t == 0) ? 0 : part[t - 1];
  s = excl;
  for (int i = 0; i < per; ++i) { int idx = base + i; if (idx < n) { offs[idx] = s; s += cnt[idx]; } }
  if (t == 1023) offs[n] = part[1023];
}

__global__ void fillperm_kernel(const int* __restrict__ eidx, const int* __restrict__ offs,
                                int* fill, int* perm, int E) {
  int e = blockIdx.x * 256 + threadIdx.x;
  if (e >= E) return;
  int dst = eidx[E + e];
  int pos = offs[dst] + atomicAdd(&fill[dst], 1);
  perm[pos] = e;
}

// Per-layer weight conversion: Bt[n][seg*768+kk] = bf16( seg==0 ? roots[kk][n] : W[seg-1][kk][n] )
__global__ void wcat_kernel(const float* __restrict__ W, const float* __restrict__ R, u16* __restrict__ Bt) {
  __shared__ float t[32 * 33];
  int b = blockIdx.x;
  int s = b / 576, rem = b % 576;
  int kt = rem / 24, nt = rem % 24;
  const float* src = (s == 0) ? R : (W + (size_t)(s - 1) * DD * DD);
  int tj = threadIdx.x & 31, ti = threadIdx.x >> 5;  // ti 0..7
#pragma unroll
  for (int i = 0; i < 4; ++i) {
    int kk = kt * 32 + ti + i * 8;
    t[(ti + i * 8) * 33 + tj] = src[(size_t)kk * DD + nt * 32 + tj];
  }
  __syncthreads();
#pragma unroll
  for (int i = 0; i < 4; ++i) {
    int nn_ = nt * 32 + ti + i * 8;
    Bt[(size_t)nn_ * KK + (size_t)s * DD + kt * 32 + tj] = f2bf(t[tj * 33 + ti + i * 8]);
  }
}

// One block (192 thr) per destination node; per-thread register accumulation;
// fused own-row copy into segment 0.
__global__ __launch_bounds__(192) void aggregate_kernel(
    const u16* __restrict__ H, const int* __restrict__ esrc, const int* __restrict__ etype,
    const int* __restrict__ offs, const int* __restrict__ perm, const int* __restrict__ cnt_rel,
    u16* __restrict__ Acat, int node0, int Nn) {
  int v = node0 + blockIdx.x;
  int t = threadIdx.x;
  int j0 = t * 4;  // 192*4 = 768
  size_t rowbase = (size_t)blockIdx.x * KK;
  *(uint2*)&Acat[rowbase + j0] = *(const uint2*)&H[(size_t)v * DD + j0];
  float a0[4] = {0,0,0,0}, a1[4] = {0,0,0,0}, a2[4] = {0,0,0,0}, a3[4] = {0,0,0,0};
  float a4[4] = {0,0,0,0}, a5[4] = {0,0,0,0}, a6[4] = {0,0,0,0};
  int beg = offs[v], end = offs[v + 1];
  for (int e = beg; e < end; ++e) {
    int eid = perm[e];
    int src = esrc[eid];
    int rel = etype[eid] + 1;
    uint2 w = *(const uint2*)&H[(size_t)src * DD + j0];
    float f0 = b2f((u16)(w.x & 0xffff));
    float f1 = b2f((u16)(w.x >> 16));
    float f2 = b2f((u16)(w.y & 0xffff));
    float f3 = b2f((u16)(w.y >> 16));
    switch (rel) {
      case 0: a0[0]+=f0; a0[1]+=f1; a0[2]+=f2; a0[3]+=f3; break;
      case 1: a1[0]+=f0; a1[1]+=f1; a1[2]+=f2; a1[3]+=f3; break;
      case 2: a2[0]+=f0; a2[1]+=f1; a2[2]+=f2; a2[3]+=f3; break;
      case 3: a3[0]+=f0; a3[1]+=f1; a3[2]+=f2; a3[3]+=f3; break;
      case 4: a4[0]+=f0; a4[1]+=f1; a4[2]+=f2; a4[3]+=f3; break;
      case 5: a5[0]+=f0; a5[1]+=f1; a5[2]+=f2; a5[3]+=f3; break;
      default: a6[0]+=f0; a6[1]+=f1; a6[2]+=f2; a6[3]+=f3; break;
    }
  }
  const float* regs[NREL] = {a0, a1, a2, a3, a4, a5, a6};
#pragma unroll
  for (int r = 0; r < NREL; ++r) {
    int c = cnt_rel[(size_t)r * Nn + v];
    float inv = (c > 0) ? 1.f / (float)c : 0.f;
    const float* a = regs[r];
    u32 lo = (u32)f2bf(a[0] * inv) | ((u32)f2bf(a[1] * inv) << 16);
    u32 hi = (u32)f2bf(a[2] * inv) | ((u32)f2bf(a[3] * inv) << 16);
    uint2 o; o.x = lo; o.y = hi;
    *(uint2*)&Acat[rowbase + (size_t)(r + 1) * DD + j0] = o;
  }
}

// ---------- 256x256 4-wave GEMM: each wave 128x128 (acc 8x8), BK=32,
// 4 LDS slots (128 KB), reg frag double-buffer E/O, counted vmcnt(8).
// Rationale: 4 fat waves cut per-CU LDS-out traffic 33% vs 8 waves (the
// measured bottleneck); 1 wave/SIMD, overlap via single-wave ILP.

#define MFMA_(a_, b_, c_) __builtin_amdgcn_mfma_f32_16x16x32_bf16(a_, b_, c_, 0, 0, 0)
#define BAR   __builtin_amdgcn_s_barrier()
#define SCB   __builtin_amdgcn_sched_barrier(0)
#define VM8   asm volatile("s_waitcnt vmcnt(8)" ::: "memory")
#define VM0   asm volatile("s_waitcnt vmcnt(0)" ::: "memory")

__global__ __launch_bounds__(256, 1) void gemm4w_kernel(
    const u16* __restrict__ A, const u16* __restrict__ Bt, const float* __restrict__ bias,
    u16* __restrict__ Hout, float* __restrict__ Cout, int Mvalid, int Mtiles) {
  // slot = 256 rows x 32 k x 2B = 16 KB each for A and B; 4 slots
  __shared__ char smA[4][16384];
  __shared__ char smB[4][16384];

  int tid = threadIdx.x;
  int lane = tid & 63;
  int wv = tid >> 6;              // 0..3
  int wm = wv >> 1, wn = wv & 1;  // 2x2 wave grid, each 128x128

  // XCD-bijective block swizzle (m204), bn fastest
  int nwg = Mtiles * 3;
  int orig = (int)blockIdx.x;
  int q8 = nwg >> 3, r8 = nwg & 7;
  int xcd = orig & 7, rank = orig >> 3;
  int wg = (xcd < r8 ? xcd * (q8 + 1) : r8 * (q8 + 1) + (xcd - r8) * q8) + rank;
  int bm = wg / 3, bn = wg % 3;

  // ---- staging: linear LDS dest, inverse-swizzled global source.
  // thread t covers rows j*64 + (t>>2), chunk t&3 of a 4-chunk (64B) row;
  // source chunk = (t&3) ^ ((row>>1)&3) = (t&3) ^ ((t>>3)&3).
  int srow = tid >> 2;            // 0..63
  int sch = (tid & 3) ^ ((tid >> 3) & 3);
  const char* gA[4];
  const char* gB[4];
#pragma unroll
  for (int j = 0; j < 4; ++j) {
    int ra = bm * 256 + j * 64 + srow;
    if (ra > Mvalid - 1) ra = Mvalid - 1;
    gA[j] = (const char*)A  + (size_t)ra * (KK * 2) + sch * 16;
    gB[j] = (const char*)Bt + (size_t)(bn * 256 + j * 64 + srow) * (KK * 2) + sch * 16;
  }
  // swizzled ds_read lane offset (row stride 64B): byte = rsel*64 + ((kq^((rsel>>1)&3))*16)
  int rsel = lane & 15, kq = lane >> 4;
  int loff = rsel * 64 + ((kq ^ ((rsel >> 1) & 3)) * 16);

  f32x4 acc[8][8];
#pragma unroll
  for (int m = 0; m < 8; ++m)
#pragma unroll
    for (int n = 0; n < 8; ++n) acc[m][n] = (f32x4){0.f, 0.f, 0.f, 0.f};

#define STAGE(st, s_)                                                     \
  do {                                                                    \
    size_t ko_ = (size_t)(st) * 64;                                       \
    gload16(gA[0] + ko_, &smA[s_][tid * 16]);                             \
    gload16(gA[1] + ko_, &smA[s_][4096 + tid * 16]);                      \
    gload16(gA[2] + ko_, &smA[s_][8192 + tid * 16]);                      \
    gload16(gA[3] + ko_, &smA[s_][12288 + tid * 16]);                     \
    gload16(gB[0] + ko_, &smB[s_][tid * 16]);                             \
    gload16(gB[1] + ko_, &smB[s_][4096 + tid * 16]);                      \
    gload16(gB[2] + ko_, &smB[s_][8192 + tid * 16]);                      \
    gload16(gB[3] + ko_, &smB[s_][12288 + tid * 16]);                     \
  } while (0)

#define READF(s_, AR, BR)                                                 \
  do {                                                                    \
    _Pragma("unroll")                                                     \
    for (int m_ = 0; m_ < 8; ++m_)                                        \
      AR[m_] = *(const short8*)(&smA[s_][(wm * 128 + m_ * 16) * 64 + loff]); \
    _Pragma("unroll")                                                     \
    for (int n_ = 0; n_ < 8; ++n_)                                        \
      BR[n_] = *(const short8*)(&smB[s_][(wn * 128 + n_ * 16) * 64 + loff]); \
  } while (0)

#define MFMA64(AR, BR)                                                    \
  do {                                                                    \
    _Pragma("unroll")                                                     \
    for (int m_ = 0; m_ < 8; ++m_)                                        \
      _Pragma("unroll")                                                   \
      for (int n_ = 0; n_ < 8; ++n_)                                      \
        acc[m_][n_] = MFMA_(AR[m_], BR[n_], acc[m_][n_]);                 \
  } while (0)

// half: stage step sSt into slot sSl; retire older stage; barrier;
// read step (into RA/RB) from slot rSl; MFMA on other frag set (MA/MB).
#define HALF(sSt, sSl, rSl, RA, RB, MA, MB)                               \
  do {                                                                    \
    STAGE(sSt, sSl);                                                      \
    VM8; BAR; SCB;                                                        \
    READF(rSl, RA, RB);                                                   \
    MFMA64(MA, MB);                                                       \
  } while (0)

  short8 aE[8], bE[8], aO[8], bO[8];

  // prologue: stage steps 0,1; retire step-0 stage; read step-0 frags
  STAGE(0, 0);
  STAGE(1, 1);
  VM8; BAR; SCB;
  READF(0, aE, bE);

  // main loop: steps t..t+3 per iteration (slots static: step x -> slot x&3)
  for (int t = 0; t < 188; t += 4) {
    HALF(t + 2, 2, 1, aO, bO, aE, bE);  // read t+1, MFMA t
    HALF(t + 3, 3, 2, aE, bE, aO, bO);  // read t+2, MFMA t+1
    HALF(t + 4, 0, 3, aO, bO, aE, bE);  // read t+3, MFMA t+2
    HALF(t + 5, 1, 0, aE, bE, aO, bO);  // read t+4, MFMA t+3
  }
  // peel steps 188..191 (stages 190,191; then drain)
  HALF(190, 2, 1, aO, bO, aE, bE);      // read 189, MFMA 188
  HALF(191, 3, 2, aE, bE, aO, bO);      // read 190, MFMA 189
  VM0; BAR; SCB;
  READF(3, aO, bO);                     // read 191
  MFMA64(aE, bE);                       // MFMA 190
  MFMA64(aO, bO);                       // MFMA 191

#undef HALF
#undef MFMA64
#undef READF
#undef STAGE

  // ---- epilogue: bias + ReLU, write bf16 h_next / f32 out ----
  int rif = (lane >> 4) * 4;
  int cidx = lane & 15;
#pragma unroll
  for (int m = 0; m < 8; ++m) {
    int rl = bm * 256 + wm * 128 + m * 16 + rif;
#pragma unroll
    for (int n = 0; n < 8; ++n) {
      int c = bn * 256 + wn * 128 + n * 16 + cidx;
      float bv = bias[c];
#pragma unroll
      for (int j = 0; j < 4; ++j) {
        int r = rl + j;
        if (r < Mvalid) {
          float v = acc[m][n][j] + bv;
          v = v > 0.f ? v : 0.f;
          if (Hout) Hout[(size_t)r * DD + c] = f2bf(v);
          if (Cout) Cout[(size_t)r * DD + c] = v;
        }
      }
    }
  }
}

// ---------- host ----------

static inline size_t alignup(size_t x, size_t a) { return (x + a - 1) & ~(a - 1); }

extern "C" void kernel_launch(void* const* d_in, const int* in_sizes, int n_in,
                              void* d_out, int out_size, void* d_ws, size_t ws_size,
                              hipStream_t stream) {
  const float* x       = (const float*)d_in[0];
  const int*   eidx    = (const int*)d_in[1];
  const int*   etype   = (const int*)d_in[2];
  const float* weights = (const float*)d_in[3];
  const float* roots   = (const float*)d_in[4];
  const float* biases  = (const float*)d_in[5];
  float* out = (float*)d_out;

  const int Nn = in_sizes[0] / DD;  // 20000
  const int E  = in_sizes[2];       // 100000

  char* p = (char*)d_ws;
  size_t off = 0;
  auto carve = [&](size_t bytes) -> char* {
    char* r = p + off;
    off = alignup(off + bytes, 256);
    return r;
  };
  u16* H0      = (u16*)carve((size_t)Nn * DD * 2);
  u16* Bt      = (u16*)carve((size_t)DD * KK * 2);
  int* cnt_rel = (int*)carve((size_t)NREL * Nn * 4);
  int* cnt_dst = (int*)carve((size_t)Nn * 4);
  int* offs    = (int*)carve((size_t)(Nn + 1) * 4);
  int* fill    = (int*)carve((size_t)Nn * 4);
  int* perm    = (int*)carve((size_t)E * 4);

  size_t rem = (ws_size > off) ? (ws_size - off) : 0;
  int McCap = (int)(rem / ((size_t)KK * 2));
  int Mpad = ((Nn + 255) / 256) * 256;
  int Mc = (McCap < Mpad) ? (McCap & ~255) : Mpad;
  if (Mc < 256) return;  // workspace too small — fail visibly rather than corrupt
  u16* Acat = (u16*)(p + off);
  int nchunks = (Nn + Mc - 1) / Mc;
  u16* H1 = (u16*)d_out;  // bf16 ping buffer inside d_out

  (void)hipMemsetAsync(cnt_rel, 0, (size_t)NREL * Nn * 4, stream);
  (void)hipMemsetAsync(cnt_dst, 0, (size_t)Nn * 4, stream);
  (void)hipMemsetAsync(fill, 0, (size_t)Nn * 4, stream);

  int eg = (E + 255) / 256;
  count_kernel<<<eg, 256, 0, stream>>>(eidx, etype, cnt_dst, cnt_rel, E, Nn);
  scan_kernel<<<1, 1024, 0, stream>>>(cnt_dst, offs, Nn);
  fillperm_kernel<<<eg, 256, 0, stream>>>(eidx, offs, fill, perm, E);
  cast_x_kernel<<<2048, 256, 0, stream>>>(x, H0, (size_t)Nn * DD);

  const u16* Hin = H0;
  u16* Hnext = H1;
  for (int l = 0; l < NLAYERS; ++l) {
    wcat_kernel<<<8 * 576, 256, 0, stream>>>(weights + (size_t)l * NREL * DD * DD,
                                             roots + (size_t)l * DD * DD, Bt);
    for (int c = 0; c < nchunks; ++c) {
      int node0 = c * Mc;
      int nn = (Nn - node0 < Mc) ? (Nn - node0) : Mc;
      aggregate_kernel<<<nn, 192, 0, stream>>>(Hin, eidx, etype, offs, perm, cnt_rel,
                                               Acat, node0, Nn);
      int mt = (nn + 255) / 256;
      u16* ho = (l < NLAYERS - 1) ? (Hnext + (size_t)node0 * DD) : nullptr;
      float* co = (l == NLAYERS - 1) ? (out + (size_t)node0 * DD) : nullptr;
      gemm4w_kernel<<<mt * 3, 256, 0, stream>>>(Acat, Bt, biases + (size_t)l * DD, ho, co, nn, mt);
    }
    const u16* t_ = Hin;
    Hin = Hnext;
    Hnext = (u16*)t_;
  }
}